// Round 26
// baseline (135.039 us; speedup 1.0000x reference)
//
#include <hip/hip_runtime.h>
#include <hip/hip_bf16.h>

typedef _Float16 f16;
typedef __attribute__((ext_vector_type(8))) f16 h8;
typedef __attribute__((ext_vector_type(4))) float f32x4;
typedef __attribute__((ext_vector_type(8))) short short8;

static __device__ __forceinline__ short h2s(f16 h) { return __builtin_bit_cast(short, h); }

#define BM 128
#define BK 32   // K-step in fp16 elems; row = 64 B (linear, required by global_load_lds)
#define PREMUL 0.18033688011112042f  // 0.125 * log2(e)

// ---------------- pre-convert: fp32 -> fp16 (hi only, RTN) ----------------
// z: 0=q 1=k 2=v 3=Wq 4=Wk 5=Wv 6=Wo
__global__ __launch_bounds__(256) void cvt_kernel(
    const float* __restrict__ q, const float* __restrict__ k, const float* __restrict__ v,
    const float* __restrict__ Wq, const float* __restrict__ Wk, const float* __restrict__ Wv,
    const float* __restrict__ Wo,
    short* __restrict__ Xqh, short* __restrict__ Xkh, short* __restrict__ Xvh,
    short* __restrict__ Wqh, short* __restrict__ Wkh,
    short* __restrict__ Wvh, short* __restrict__ Woh) {
    const int z = blockIdx.y;
    const int n = (z < 3) ? (1 << 22) : (1 << 20);
    const int idx = (blockIdx.x * 256 + threadIdx.x) * 8;
    if (idx >= n) return;
    const float* src = z == 0 ? q : z == 1 ? k : z == 2 ? v : z == 3 ? Wq : z == 4 ? Wk : z == 5 ? Wv : Wo;
    short* dh = z == 0 ? Xqh : z == 1 ? Xkh : z == 2 ? Xvh : z == 3 ? Wqh : z == 4 ? Wkh : z == 5 ? Wvh : Woh;
    const float4 a = *(const float4*)(src + idx);
    const float4 b = *(const float4*)(src + idx + 4);
    float f[8] = {a.x, a.y, a.z, a.w, b.x, b.y, b.z, b.w};
    short8 hi;
#pragma unroll
    for (int j = 0; j < 8; ++j) hi[j] = h2s((f16)f[j]);
    *(short8*)(dh + idx) = hi;
}

// ---------------- fp16-MFMA GEMM, async staging + 3-stage counted-vmcnt pipeline --------
// (measured-best R25 structure: raw s_barrier + s_waitcnt vmcnt(4), 3-set rotation)
template <int EPI>
static __device__ __forceinline__ void gemm16(const short* __restrict__ Ag,
                                              const short* __restrict__ Bhg,
                                              const float* __restrict__ bias,
                                              short* __restrict__ o0,
                                              float* __restrict__ of) {
    extern __shared__ __align__(16) short smem[];
    constexpr int SETSZ = 2 * BM * BK;  // shorts per stage-set (A + B)

    const int K = 1024;
    const int tid = threadIdx.x;
    const int lane = tid & 63;
    const int w = tid >> 6;
    const int lr = lane & 15, lg = lane >> 4;
    const int wm = (w & 1) * 64, wn = (w >> 1) * 64;
    const int m0 = blockIdx.x * BM, n0 = blockIdx.y * BM;

    const int lane2 = lane >> 2;       // 0..15: staged row within wave's 16-row slab
    const int slot8 = (lane & 3) * 8;  // 0,8,16,24 elem col offset (16 B slots)

    f32x4 acc[4][4] = {};

    const int NT = K / BK;  // 32

    auto STAGE = [&](int set, int t) {
        const int ko = t * BK;
        short* Ah = smem + set * SETSZ;
        short* Bh = Ah + BM * BK;
#pragma unroll
        for (int i = 0; i < 2; ++i) {
            const int r = i * 64 + w * 16 + lane2;
            const int ldsoff = i * 4096 + w * 1024;  // bytes
            __builtin_amdgcn_global_load_lds(Ag + (size_t)(m0 + r) * K + ko + slot8,
                                             (char*)Ah + ldsoff, 16, 0, 0);
            __builtin_amdgcn_global_load_lds(Bhg + (size_t)(n0 + r) * K + ko + slot8,
                                             (char*)Bh + ldsoff, 16, 0, 0);
        }
    };

    auto COMPUTE = [&](int set) {
        const short* Ah = smem + set * SETSZ;
        const short* Bh = Ah + BM * BK;
        h8 afh[4], bfh[4];
#pragma unroll
        for (int f = 0; f < 4; ++f) {
            afh[f] = *(const h8*)&Ah[(wm + f * 16 + lr) * BK + lg * 8];
            bfh[f] = *(const h8*)&Bh[(wn + f * 16 + lr) * BK + lg * 8];
        }
        __builtin_amdgcn_s_setprio(1);
#pragma unroll
        for (int i = 0; i < 4; i++)
#pragma unroll
            for (int j = 0; j < 4; j++)
                acc[i][j] = __builtin_amdgcn_mfma_f32_16x16x32_f16(afh[i], bfh[j], acc[i][j], 0, 0, 0);
        __builtin_amdgcn_s_setprio(0);
    };

    // prologue: stage tiles 0,1 into sets 0,1; retire tile 0's loads (keep tile 1's).
    STAGE(0, 0);
    STAGE(1, 1);
    asm volatile("s_waitcnt vmcnt(4) lgkmcnt(0)" ::: "memory");
    __builtin_amdgcn_s_barrier();
    int cur = 0, nxt2 = 2;  // set holding tile t; set to stage tile t+2 into
    for (int t = 0; t < NT; ++t) {
        if (t + 2 < NT) STAGE(nxt2, t + 2);  // loads fly across this iteration's barrier
        COMPUTE(cur);
        if (t + 2 < NT)
            asm volatile("s_waitcnt vmcnt(4) lgkmcnt(0)" ::: "memory");  // retire tile t+1
        else
            asm volatile("s_waitcnt vmcnt(0) lgkmcnt(0)" ::: "memory");  // tail drain
        __builtin_amdgcn_s_barrier();
        cur = (cur == 2) ? 0 : cur + 1;
        nxt2 = (nxt2 == 2) ? 0 : nxt2 + 1;
    }

    // epilogue. C-frag: row=(lane>>4)*4+i, col=lane&15
#pragma unroll
    for (int fn = 0; fn < 4; ++fn) {
        const int n = n0 + wn + fn * 16 + lr;
        const float bia = bias[n];
#pragma unroll
        for (int fm = 0; fm < 4; ++fm) {
#pragma unroll
            for (int i = 0; i < 4; i++) {
                const int m = m0 + wm + fm * 16 + lg * 4 + i;
                float val = acc[fm][fn][i] + bia;
                if (EPI == 0) {
                    of[(size_t)m * 1024 + n] = val;
                } else {
                    const int bb = m >> 11, s = m & 2047, hh = n >> 6, d = n & 63;
                    if (EPI == 2 || EPI == 4) {
                        if (EPI == 4) val *= PREMUL;  // fold softmax scale+log2e into Q
                        const size_t off = (((size_t)(bb * 16 + hh) * 2048 + s) << 6) + d;
                        o0[off] = h2s((f16)val);
                    } else {  // EPI == 3: transposed [B,H,64,S]
                        const size_t off = ((size_t)(bb * 16 + hh) * 64 + d) * 2048 + s;
                        o0[off] = h2s((f16)val);
                    }
                }
            }
        }
    }
}

// merged Q/K/V projection: all 1-term fp16; homogeneous branches.
// Dynamic LDS 49152 B (3 sets x 2 buffers) shared across branches.
__global__ __launch_bounds__(256) void qkv_kernel(
    const short* __restrict__ Xqh, const short* __restrict__ Xkh, const short* __restrict__ Xvh,
    const short* __restrict__ Wqh, const short* __restrict__ Wkh, const short* __restrict__ Wvh,
    const float* __restrict__ bq, const float* __restrict__ bk, const float* __restrict__ bv,
    short* __restrict__ Qh, short* __restrict__ Kh, short* __restrict__ Vt_g) {
    if (blockIdx.z == 0)
        gemm16<4>(Xqh, Wqh, bq, Qh, nullptr);     // Q: premul fp16 out
    else if (blockIdx.z == 1)
        gemm16<2>(Xkh, Wkh, bk, Kh, nullptr);     // K
    else
        gemm16<3>(Xvh, Wvh, bv, Vt_g, nullptr);   // V: transposed out
}

__global__ __launch_bounds__(256) void oproj_kernel(const short* __restrict__ Xb,
                                                    const short* __restrict__ Woh,
                                                    const float* __restrict__ bo,
                                                    float* __restrict__ out) {
    gemm16<0>(Xb, Woh, bo, nullptr, out);
}

// ---------------- flash attention with threshold mask (swapped QK^T, S-SPLIT x2) --------
// Q fp16 PRE-SCALED by PREMUL [B*H][S][64]; K fp16 [B*H][S][64];
// V fp16 TRANSPOSED [B*H][64][S]. Scores in log2 domain; 1-term QK^T; NO online max,
// so acc and l are PLAIN SUMS over keys -> key-range halves merge by addition.
// Grid (16, 32, 2): z selects KV tiles [z*16, z*16+16). Partials (f32 acc, f32 l) go to
// Pz/Lz; merge_kernel sums, divides, converts. Single-buffered K/V (LDS 37.9 KB) ->
// 4 blocks/CU x 8 waves = 32 waves/CU co-resident (2x R25).
#define PSK 76
__global__ __launch_bounds__(512) void attn_kernel(const short* __restrict__ Qh,
                                                   const short* __restrict__ Kh,
                                                   const short* __restrict__ Vg,
                                                   const float* __restrict__ rawthr,
                                                   float* __restrict__ P0, float* __restrict__ P1,
                                                   float* __restrict__ L0, float* __restrict__ L1) {
    __shared__ __align__(16) short Ksh[64][72];
    __shared__ __align__(16) short Vt[64][72];      // [feat][key]
    __shared__ __align__(16) short Ps[8][16][PSK];  // per-wave P tile [q][key]
    const int tid = threadIdx.x, lane = tid & 63, w = tid >> 6;  // w = 0..7
    const int lr = lane & 15, lg = lane >> 4;
    const int bh = blockIdx.y;
    const int z = blockIdx.z;
    const int t0 = z * 16;  // this block's KV tile range [t0, t0+16)
    const int h = bh & 15;
    const size_t base = (size_t)bh * 2048 * 64;
    const float LOG2E = 1.4426950408889634f;
    const float rt = rawthr[h];
    const float thr = rt > 20.f ? rt : log1pf(expf(rt));
    const float thr2 = thr * LOG2E;  // threshold in log2 domain (scores arrive pre-scaled)
    const int qrow = blockIdx.x * 128 + w * 16;
    float* __restrict__ Pz = z ? P1 : P0;
    float* __restrict__ Lz = z ? L1 : L0;

    h8 qf[2];
#pragma unroll
    for (int kk = 0; kk < 2; ++kk)
        qf[kk] = *(const h8*)(Qh + base + (size_t)(qrow + lr) * 64 + kk * 32 + lg * 8);

    f32x4 acc[4] = {};
    float lpart = 0.f;  // per-lane partial sum (this lane's 16 keys/iter); reduced at end

    const int skey = tid >> 3;      // 0..63 (512 threads: one short8 per thread per buffer)
    const int sfe = (tid & 7) * 8;  // 0..56 step 8 (16 B granules)
    short8 khreg, vreg;
    {
        khreg = *(const short8*)(Kh + base + (size_t)(t0 * 64 + skey) * 64 + sfe);
        vreg = *(const short8*)(Vg + base + (size_t)skey * 2048 + t0 * 64 + sfe);
    }

    for (int kt = t0; kt < t0 + 16; ++kt) {
        __syncthreads();
        *(short8*)&Ksh[skey][sfe] = khreg;
        *(short8*)&Vt[skey][sfe] = vreg;
        __syncthreads();
        if (kt + 1 < t0 + 16) {
            khreg = *(const short8*)(Kh + base + (size_t)((kt + 1) * 64 + skey) * 64 + sfe);
            vreg = *(const short8*)(Vg + base + (size_t)skey * 2048 + (kt + 1) * 64 + sfe);
        }
        // S^T = K Q^T (1-term fp16); output already log2-domain
        f32x4 sc[4] = {};
        __builtin_amdgcn_s_setprio(1);
#pragma unroll
        for (int fn = 0; fn < 4; ++fn) {
#pragma unroll
            for (int kk = 0; kk < 2; ++kk) {
                const h8 khf = *(const h8*)&Ksh[fn * 16 + lr][kk * 32 + lg * 8];
                sc[fn] = __builtin_amdgcn_mfma_f32_16x16x32_f16(khf, qf[kk], sc[fn], 0, 0, 0);
            }
        }
        __builtin_amdgcn_s_setprio(0);
        // threshold-mask -> p = exp2(s) (0 if masked); accumulate partial row sum
#pragma unroll
        for (int fn = 0; fn < 4; ++fn)
#pragma unroll
            for (int i = 0; i < 4; ++i) {
                float s = sc[fn][i];
                s = (s <= thr2) ? -1e30f : s;
                const float p = __builtin_amdgcn_exp2f(s);
                sc[fn][i] = p;
                lpart += p;
            }
        // P -> LDS: packed RTZ f32->f16 pairs, conflict-free 8B writes (wave-local buffer)
#pragma unroll
        for (int fn = 0; fn < 4; ++fn) {
            const unsigned int p01 =
                __builtin_bit_cast(unsigned int, __builtin_amdgcn_cvt_pkrtz(sc[fn][0], sc[fn][1]));
            const unsigned int p23 =
                __builtin_bit_cast(unsigned int, __builtin_amdgcn_cvt_pkrtz(sc[fn][2], sc[fn][3]));
            uint2 u;
            u.x = p01;
            u.y = p23;
            *(uint2*)&Ps[w][lr][fn * 16 + lg * 4] = u;
        }
        // O += P V
        h8 pa[2];
#pragma unroll
        for (int kk = 0; kk < 2; ++kk)
            pa[kk] = *(const h8*)&Ps[w][lr][kk * 32 + lg * 8];
        __builtin_amdgcn_s_setprio(1);
#pragma unroll
        for (int kk = 0; kk < 2; ++kk)
#pragma unroll
            for (int fv = 0; fv < 4; ++fv) {
                const h8 vf = *(const h8*)&Vt[fv * 16 + lr][kk * 32 + lg * 8];
                acc[fv] = __builtin_amdgcn_mfma_f32_16x16x32_f16(pa[kk], vf, acc[fv], 0, 0, 0);
            }
        __builtin_amdgcn_s_setprio(0);
    }
    // partial row sum: combine the 4 lg replicas; write f32 partials (no divide here)
    float lrun = lpart;
    lrun += __shfl_xor(lrun, 16);
    lrun += __shfl_xor(lrun, 32);
    if (lg == 0) Lz[bh * 2048 + qrow + lr] = lrun;
#pragma unroll
    for (int i = 0; i < 4; ++i) {
        const int s = qrow + lg * 4 + i;
#pragma unroll
        for (int fv = 0; fv < 4; ++fv) {
            const int d = fv * 16 + lr;
            Pz[(((size_t)(bh * 2048 + s)) << 6) + d] = acc[fv][i];
        }
    }
}

// ---------------- merge: x = (a0+a1)/(l0+l1) -> fp16 Xb [B,S,H*64] ----------------
__global__ __launch_bounds__(256) void merge_kernel(const float* __restrict__ P0,
                                                    const float* __restrict__ P1,
                                                    const float* __restrict__ L0,
                                                    const float* __restrict__ L1,
                                                    short* __restrict__ Xb) {
    const int t = blockIdx.x * 256 + threadIdx.x;  // 524288 threads: (row, 8-col group)
    const int row = t >> 3;                        // bh*2048 + s, 0..65535
    const int c8 = (t & 7) * 8;
    const float inv = 1.f / (L0[row] + L1[row]);
    const size_t po = (size_t)row * 64 + c8;
    const float4 a0 = *(const float4*)(P0 + po);
    const float4 a1 = *(const float4*)(P0 + po + 4);
    const float4 b0 = *(const float4*)(P1 + po);
    const float4 b1 = *(const float4*)(P1 + po + 4);
    float vsum[8] = {a0.x + b0.x, a0.y + b0.y, a0.z + b0.z, a0.w + b0.w,
                     a1.x + b1.x, a1.y + b1.y, a1.z + b1.z, a1.w + b1.w};
    short8 o;
#pragma unroll
    for (int j = 0; j < 8; ++j) o[j] = h2s((f16)(vsum[j] * inv));
    const int bb = row >> 15, hh = (row >> 11) & 15, s = row & 2047;
    *(short8*)(Xb + (((size_t)(bb * 2048 + s)) << 10) + (hh << 6) + c8) = o;
}

extern "C" void kernel_launch(void* const* d_in, const int* in_sizes, int n_in,
                              void* d_out, int out_size, void* d_ws, size_t ws_size,
                              hipStream_t stream) {
    const float* q = (const float*)d_in[0];
    const float* k = (const float*)d_in[1];
    const float* v = (const float*)d_in[2];
    const float* Wq = (const float*)d_in[3];
    const float* bq = (const float*)d_in[4];
    const float* Wk = (const float*)d_in[5];
    const float* bk = (const float*)d_in[6];
    const float* Wv = (const float*)d_in[7];
    const float* bv = (const float*)d_in[8];
    const float* Wo = (const float*)d_in[9];
    const float* bo = (const float*)d_in[10];
    const float* thr = (const float*)d_in[11];
    float* out = (float*)d_out;

    const size_t MX = (size_t)4 * 1024 * 1024;  // X-sized: 4M elems
    const size_t MW = (size_t)1024 * 1024;      // W-sized: 1M elems
    short* Woh = (short*)d_ws;
    short* Xqh = Woh + MW;
    short* Xkh = Xqh + MX;
    short* Xvh = Xkh + MX;
    short* Wqh = Xvh + MX;
    short* Wkh = Wqh + MW;
    short* Wvh = Wkh + MW;
    short* Qh = Wvh + MW;
    short* Kh = Qh + MX;
    short* Vt = Kh + MX;
    float* P1 = (float*)(Vt + MX);      // 4M floats (16 MB)
    short* Xb = (short*)(P1 + MX);      // 4M shorts (8 MB)
    float* L0 = (float*)(Xb + MX);      // 65536 floats
    float* L1 = L0 + 65536;
    float* P0 = (float*)Xqh;            // aliases Xqh+Xkh (16 MB, dead after qkv)

    const size_t LDS_GEMM = 3 * 2 * BM * BK * sizeof(short);  // 49152 (3 sets x 2 bufs)

    cvt_kernel<<<dim3(2048, 7), 256, 0, stream>>>(q, k, v, Wq, Wk, Wv, Wo,
                                                  Xqh, Xkh, Xvh,
                                                  Wqh, Wkh, Wvh, Woh);
    qkv_kernel<<<dim3(32, 8, 3), 256, LDS_GEMM, stream>>>(Xqh, Xkh, Xvh,
                                                          Wqh, Wkh, Wvh,
                                                          bq, bk, bv, Qh, Kh, Vt);
    attn_kernel<<<dim3(16, 32, 2), 512, 0, stream>>>(Qh, Kh, Vt, thr, P0, P1, L0, L1);
    merge_kernel<<<dim3(2048), 256, 0, stream>>>(P0, P1, L0, L1, Xb);
    oproj_kernel<<<dim3(32, 8), 256, LDS_GEMM, stream>>>(Xb, Woh, bo, out);
}

// Round 27
// 125.159 us; speedup vs baseline: 1.0789x; 1.0789x over previous
//
#include <hip/hip_runtime.h>
#include <hip/hip_bf16.h>

typedef _Float16 f16;
typedef __attribute__((ext_vector_type(8))) f16 h8;
typedef __attribute__((ext_vector_type(4))) float f32x4;
typedef __attribute__((ext_vector_type(8))) short short8;

static __device__ __forceinline__ short h2s(f16 h) { return __builtin_bit_cast(short, h); }

#define BM 128
#define BK 32   // K-step in fp16 elems; row = 64 B (linear, required by global_load_lds)
#define PREMUL 0.18033688011112042f  // 0.125 * log2(e)

// ---------------- pre-convert: fp32 -> fp16 (hi only, RTN) ----------------
// z: 0=q 1=k 2=v 3=Wq 4=Wk 5=Wv 6=Wo
__global__ __launch_bounds__(256) void cvt_kernel(
    const float* __restrict__ q, const float* __restrict__ k, const float* __restrict__ v,
    const float* __restrict__ Wq, const float* __restrict__ Wk, const float* __restrict__ Wv,
    const float* __restrict__ Wo,
    short* __restrict__ Xqh, short* __restrict__ Xkh, short* __restrict__ Xvh,
    short* __restrict__ Wqh, short* __restrict__ Wkh,
    short* __restrict__ Wvh, short* __restrict__ Woh) {
    const int z = blockIdx.y;
    const int n = (z < 3) ? (1 << 22) : (1 << 20);
    const int idx = (blockIdx.x * 256 + threadIdx.x) * 8;
    if (idx >= n) return;
    const float* src = z == 0 ? q : z == 1 ? k : z == 2 ? v : z == 3 ? Wq : z == 4 ? Wk : z == 5 ? Wv : Wo;
    short* dh = z == 0 ? Xqh : z == 1 ? Xkh : z == 2 ? Xvh : z == 3 ? Wqh : z == 4 ? Wkh : z == 5 ? Wvh : Woh;
    const float4 a = *(const float4*)(src + idx);
    const float4 b = *(const float4*)(src + idx + 4);
    float f[8] = {a.x, a.y, a.z, a.w, b.x, b.y, b.z, b.w};
    short8 hi;
#pragma unroll
    for (int j = 0; j < 8; ++j) hi[j] = h2s((f16)f[j]);
    *(short8*)(dh + idx) = hi;
}

// ---------------- fp16-MFMA GEMM, async staging + 3-stage counted-vmcnt pipeline --------
// DYNAMIC LDS: 3 stage-sets x 2 buffers of BM*BK shorts (8 KB each), LINEAR rows. 48 KB.
// T4: raw s_barrier with MANUAL s_waitcnt vmcnt(4) lgkmcnt(0) -- the 4 newest loads
// (tile t+2) stay in flight ACROSS the barrier; only tile t+1's loads retire. 3-set
// rotation guarantees no overwrite race. Tail falls back to vmcnt(0).
// A,B fp16 [.][1024], 1-term.
// EPI: 0 = fp32 out [M][1024]; 2 = fp16 to o0 [B,H,S,64]; 3 = fp16 TRANSPOSED [B,H,64,S];
//      4 = fp16 to o0 [B,H,S,64] PRE-SCALED by PREMUL (Q path).
template <int EPI>
static __device__ __forceinline__ void gemm16(const short* __restrict__ Ag,
                                              const short* __restrict__ Bhg,
                                              const float* __restrict__ bias,
                                              short* __restrict__ o0,
                                              float* __restrict__ of) {
    extern __shared__ __align__(16) short smem[];
    constexpr int SETSZ = 2 * BM * BK;  // shorts per stage-set (A + B)

    const int K = 1024;
    const int tid = threadIdx.x;
    const int lane = tid & 63;
    const int w = tid >> 6;
    const int lr = lane & 15, lg = lane >> 4;
    const int wm = (w & 1) * 64, wn = (w >> 1) * 64;
    const int m0 = blockIdx.x * BM, n0 = blockIdx.y * BM;

    const int lane2 = lane >> 2;       // 0..15: staged row within wave's 16-row slab
    const int slot8 = (lane & 3) * 8;  // 0,8,16,24 elem col offset (16 B slots)

    f32x4 acc[4][4] = {};

    const int NT = K / BK;  // 32

    auto STAGE = [&](int set, int t) {
        const int ko = t * BK;
        short* Ah = smem + set * SETSZ;
        short* Bh = Ah + BM * BK;
#pragma unroll
        for (int i = 0; i < 2; ++i) {
            const int r = i * 64 + w * 16 + lane2;
            const int ldsoff = i * 4096 + w * 1024;  // bytes
            __builtin_amdgcn_global_load_lds(Ag + (size_t)(m0 + r) * K + ko + slot8,
                                             (char*)Ah + ldsoff, 16, 0, 0);
            __builtin_amdgcn_global_load_lds(Bhg + (size_t)(n0 + r) * K + ko + slot8,
                                             (char*)Bh + ldsoff, 16, 0, 0);
        }
    };

    auto COMPUTE = [&](int set) {
        const short* Ah = smem + set * SETSZ;
        const short* Bh = Ah + BM * BK;
        h8 afh[4], bfh[4];
#pragma unroll
        for (int f = 0; f < 4; ++f) {
            afh[f] = *(const h8*)&Ah[(wm + f * 16 + lr) * BK + lg * 8];
            bfh[f] = *(const h8*)&Bh[(wn + f * 16 + lr) * BK + lg * 8];
        }
        __builtin_amdgcn_s_setprio(1);
#pragma unroll
        for (int i = 0; i < 4; i++)
#pragma unroll
            for (int j = 0; j < 4; j++)
                acc[i][j] = __builtin_amdgcn_mfma_f32_16x16x32_f16(afh[i], bfh[j], acc[i][j], 0, 0, 0);
        __builtin_amdgcn_s_setprio(0);
    };

    // prologue: stage tiles 0,1 into sets 0,1; retire tile 0's loads (keep tile 1's).
    STAGE(0, 0);
    STAGE(1, 1);
    asm volatile("s_waitcnt vmcnt(4) lgkmcnt(0)" ::: "memory");
    __builtin_amdgcn_s_barrier();
    int cur = 0, nxt2 = 2;  // set holding tile t; set to stage tile t+2 into
    for (int t = 0; t < NT; ++t) {
        if (t + 2 < NT) STAGE(nxt2, t + 2);  // loads fly across this iteration's barrier
        COMPUTE(cur);
        if (t + 2 < NT)
            asm volatile("s_waitcnt vmcnt(4) lgkmcnt(0)" ::: "memory");  // retire tile t+1
        else
            asm volatile("s_waitcnt vmcnt(0) lgkmcnt(0)" ::: "memory");  // tail drain
        __builtin_amdgcn_s_barrier();
        cur = (cur == 2) ? 0 : cur + 1;
        nxt2 = (nxt2 == 2) ? 0 : nxt2 + 1;
    }

    // epilogue. C-frag: row=(lane>>4)*4+i, col=lane&15
#pragma unroll
    for (int fn = 0; fn < 4; ++fn) {
        const int n = n0 + wn + fn * 16 + lr;
        const float bia = bias[n];
#pragma unroll
        for (int fm = 0; fm < 4; ++fm) {
#pragma unroll
            for (int i = 0; i < 4; i++) {
                const int m = m0 + wm + fm * 16 + lg * 4 + i;
                float val = acc[fm][fn][i] + bia;
                if (EPI == 0) {
                    of[(size_t)m * 1024 + n] = val;
                } else {
                    const int bb = m >> 11, s = m & 2047, hh = n >> 6, d = n & 63;
                    if (EPI == 2 || EPI == 4) {
                        if (EPI == 4) val *= PREMUL;  // fold softmax scale+log2e into Q
                        const size_t off = (((size_t)(bb * 16 + hh) * 2048 + s) << 6) + d;
                        o0[off] = h2s((f16)val);
                    } else {  // EPI == 3: transposed [B,H,64,S]
                        const size_t off = ((size_t)(bb * 16 + hh) * 64 + d) * 2048 + s;
                        o0[off] = h2s((f16)val);
                    }
                }
            }
        }
    }
}

// merged Q/K/V projection: all 1-term fp16; homogeneous branches.
// Dynamic LDS 49152 B (3 sets x 2 buffers) shared across branches.
__global__ __launch_bounds__(256) void qkv_kernel(
    const short* __restrict__ Xqh, const short* __restrict__ Xkh, const short* __restrict__ Xvh,
    const short* __restrict__ Wqh, const short* __restrict__ Wkh, const short* __restrict__ Wvh,
    const float* __restrict__ bq, const float* __restrict__ bk, const float* __restrict__ bv,
    short* __restrict__ Qh, short* __restrict__ Kh, short* __restrict__ Vt_g) {
    if (blockIdx.z == 0)
        gemm16<4>(Xqh, Wqh, bq, Qh, nullptr);     // Q: premul fp16 out
    else if (blockIdx.z == 1)
        gemm16<2>(Xkh, Wkh, bk, Kh, nullptr);     // K
    else
        gemm16<3>(Xvh, Wvh, bv, Vt_g, nullptr);   // V: transposed out
}

__global__ __launch_bounds__(256) void oproj_kernel(const short* __restrict__ Xb,
                                                    const short* __restrict__ Woh,
                                                    const float* __restrict__ bo,
                                                    float* __restrict__ out) {
    gemm16<0>(Xb, Woh, bo, nullptr, out);
}

// ---------------- flash attention with threshold mask (swapped QK^T) --------------------
// Q fp16 PRE-SCALED by PREMUL [B*H][S][64]; K fp16 [B*H][S][64];
// V fp16 TRANSPOSED [B*H][64][S]. Scores land in log2 domain. 1-term QK^T.
// NO online max: |score*log2e| <= ~9; masked keys -> p = 0 exactly.
// 8-WAVE BLOCKS + K AND V DOUBLE-BUFFERED: ONE barrier per KV tile (measured-best R24/R25).
#define PSK 76
__global__ __launch_bounds__(512) void attn_kernel(const short* __restrict__ Qh,
                                                   const short* __restrict__ Kh,
                                                   const short* __restrict__ Vg,
                                                   const float* __restrict__ rawthr,
                                                   short* __restrict__ Xb) {
    __shared__ __align__(16) short Ksh[2][64][72];  // [set][key][feat]
    __shared__ __align__(16) short Vt[2][64][72];   // [set][feat][key]
    __shared__ __align__(16) short Ps[8][16][PSK];  // per-wave P tile [q][key]
    const int tid = threadIdx.x, lane = tid & 63, w = tid >> 6;  // w = 0..7
    const int lr = lane & 15, lg = lane >> 4;
    const int bh = blockIdx.y;
    const int b = bh >> 4, h = bh & 15;
    const size_t base = (size_t)bh * 2048 * 64;
    const float LOG2E = 1.4426950408889634f;
    const float rt = rawthr[h];
    const float thr = rt > 20.f ? rt : log1pf(expf(rt));
    const float thr2 = thr * LOG2E;  // threshold in log2 domain (scores arrive pre-scaled)
    const int qrow = blockIdx.x * 128 + w * 16;

    h8 qf[2];
#pragma unroll
    for (int kk = 0; kk < 2; ++kk)
        qf[kk] = *(const h8*)(Qh + base + (size_t)(qrow + lr) * 64 + kk * 32 + lg * 8);

    f32x4 acc[4] = {};
    float lpart = 0.f;  // per-lane partial sum (this lane's 16 keys/iter); reduced at end

    const int skey = tid >> 3;      // 0..63 (512 threads: one short8 per thread per buffer)
    const int sfe = (tid & 7) * 8;  // 0..56 step 8 (16 B granules)
    short8 khreg, vreg;
    // prologue: tile 0 -> set 0, one barrier
    {
        khreg = *(const short8*)(Kh + base + (size_t)skey * 64 + sfe);
        vreg = *(const short8*)(Vg + base + (size_t)skey * 2048 + sfe);
        *(short8*)&Ksh[0][skey][sfe] = khreg;
        *(short8*)&Vt[0][skey][sfe] = vreg;
    }
    __syncthreads();

    for (int kt = 0; kt < 32; ++kt) {
        const int cur = kt & 1;
        const bool more = (kt + 1 < 32);
        if (more) {  // issue next tile's global loads; they fly under this tile's compute
            khreg = *(const short8*)(Kh + base + (size_t)((kt + 1) * 64 + skey) * 64 + sfe);
            vreg = *(const short8*)(Vg + base + (size_t)skey * 2048 + (kt + 1) * 64 + sfe);
        }
        // S^T = K Q^T (1-term fp16); output already log2-domain
        f32x4 sc[4] = {};
        __builtin_amdgcn_s_setprio(1);
#pragma unroll
        for (int fn = 0; fn < 4; ++fn) {
#pragma unroll
            for (int kk = 0; kk < 2; ++kk) {
                const h8 khf = *(const h8*)&Ksh[cur][fn * 16 + lr][kk * 32 + lg * 8];
                sc[fn] = __builtin_amdgcn_mfma_f32_16x16x32_f16(khf, qf[kk], sc[fn], 0, 0, 0);
            }
        }
        __builtin_amdgcn_s_setprio(0);
        // threshold-mask -> p = exp2(s) (0 if masked); accumulate partial row sum
#pragma unroll
        for (int fn = 0; fn < 4; ++fn)
#pragma unroll
            for (int i = 0; i < 4; ++i) {
                float s = sc[fn][i];
                s = (s <= thr2) ? -1e30f : s;
                const float p = __builtin_amdgcn_exp2f(s);
                sc[fn][i] = p;
                lpart += p;
            }
        // P -> LDS: packed RTZ f32->f16 pairs, conflict-free 8B writes (wave-local buffer)
#pragma unroll
        for (int fn = 0; fn < 4; ++fn) {
            const unsigned int p01 =
                __builtin_bit_cast(unsigned int, __builtin_amdgcn_cvt_pkrtz(sc[fn][0], sc[fn][1]));
            const unsigned int p23 =
                __builtin_bit_cast(unsigned int, __builtin_amdgcn_cvt_pkrtz(sc[fn][2], sc[fn][3]));
            uint2 u;
            u.x = p01;
            u.y = p23;
            *(uint2*)&Ps[w][lr][fn * 16 + lg * 4] = u;
        }
        // O += P V (Ps read is wave-local; lgkm-ordered within wave)
        h8 pa[2];
#pragma unroll
        for (int kk = 0; kk < 2; ++kk)
            pa[kk] = *(const h8*)&Ps[w][lr][kk * 32 + lg * 8];
        __builtin_amdgcn_s_setprio(1);
#pragma unroll
        for (int kk = 0; kk < 2; ++kk)
#pragma unroll
            for (int fv = 0; fv < 4; ++fv) {
                const h8 vf = *(const h8*)&Vt[cur][fv * 16 + lr][kk * 32 + lg * 8];
                acc[fv] = __builtin_amdgcn_mfma_f32_16x16x32_f16(pa[kk], vf, acc[fv], 0, 0, 0);
            }
        __builtin_amdgcn_s_setprio(0);
        // write-late: land next tile into the other set (last read at kt-1; safe)
        if (more) {
            *(short8*)&Ksh[cur ^ 1][skey][sfe] = khreg;
            *(short8*)&Vt[cur ^ 1][skey][sfe] = vreg;
        }
        __syncthreads();  // publishes set cur^1 for iteration kt+1
    }
    // full row sum: combine the 4 lg replicas (lanes lr, lr+16, lr+32, lr+48)
    float lrun = lpart;
    lrun += __shfl_xor(lrun, 16);
    lrun += __shfl_xor(lrun, 32);
    // epilogue: x = acc / l -> fp16 [B,S,H*64]
#pragma unroll
    for (int i = 0; i < 4; ++i) {
        const float lq = __shfl(lrun, lg * 4 + i);
        const float inv = 1.f / lq;
        const int s = qrow + lg * 4 + i;
#pragma unroll
        for (int fv = 0; fv < 4; ++fv) {
            const int d = fv * 16 + lr;
            Xb[((size_t)(b * 2048 + s) << 10) + (h << 6) + d] = h2s((f16)(acc[fv][i] * inv));
        }
    }
}

extern "C" void kernel_launch(void* const* d_in, const int* in_sizes, int n_in,
                              void* d_out, int out_size, void* d_ws, size_t ws_size,
                              hipStream_t stream) {
    const float* q = (const float*)d_in[0];
    const float* k = (const float*)d_in[1];
    const float* v = (const float*)d_in[2];
    const float* Wq = (const float*)d_in[3];
    const float* bq = (const float*)d_in[4];
    const float* Wk = (const float*)d_in[5];
    const float* bk = (const float*)d_in[6];
    const float* Wv = (const float*)d_in[7];
    const float* bv = (const float*)d_in[8];
    const float* Wo = (const float*)d_in[9];
    const float* bo = (const float*)d_in[10];
    const float* thr = (const float*)d_in[11];
    float* out = (float*)d_out;

    const size_t MX = (size_t)4 * 1024 * 1024;  // X-sized: 4M elems
    const size_t MW = (size_t)1024 * 1024;      // W-sized: 1M elems
    short* Xqh = (short*)d_ws;
    short* Xkh = Xqh + MX;
    short* Xvh = Xkh + MX;
    short* Wqh = Xvh + MX;
    short* Wkh = Wqh + MW;
    short* Wvh = Wkh + MW;
    short* Woh = Wvh + MW;
    short* Qh = Woh + MW;
    short* Kh = Qh + MX;
    short* Vt = Kh + MX;
    short* Xb = Xkh;  // alias: Xk dead after qkv_kernel

    const size_t LDS_GEMM = 3 * 2 * BM * BK * sizeof(short);  // 49152 (3 sets x 2 bufs)

    cvt_kernel<<<dim3(2048, 7), 256, 0, stream>>>(q, k, v, Wq, Wk, Wv, Wo,
                                                  Xqh, Xkh, Xvh,
                                                  Wqh, Wkh, Wvh, Woh);
    qkv_kernel<<<dim3(32, 8, 3), 256, LDS_GEMM, stream>>>(Xqh, Xkh, Xvh,
                                                          Wqh, Wkh, Wvh,
                                                          bq, bk, bv, Qh, Kh, Vt);
    attn_kernel<<<dim3(16, 32), 512, 0, stream>>>(Qh, Kh, Vt, thr, Xb);
    oproj_kernel<<<dim3(32, 8), 256, LDS_GEMM, stream>>>(Xb, Woh, bo, out);
}